// Round 9
// baseline (54.786 us; speedup 1.0000x reference)
//
#include <hip/hip_runtime.h>
#include <hip/hip_bf16.h>

// SHConv via bf16 MFMA: out[b,o,n] = sum_i x[b,i,n] * W_{l(n)}[i,o], l(n)=floor(sqrt(n))
// x: (32,64,6561) f32, weight: (64,64,17,1) f32, out: (32,64,6561) f32
//
// R8: persistent pipelined waves (direct R3/R4 structure, no LDS, no barriers).
// wave = (slot = 16-pos chunk of degree l, 4 consecutive batches).
//   - A-fragments (weights) loaded ONCE per wave, reused for all 4 batches.
//   - B-loads software-pipelined depth-2 through two NAMED register buffers
//     (hand-unrolled -> all indices compile-time, nothing goes to scratch):
//     load(b0); load(b1); compute(b0); load(b2); compute(b1); load(b3);
//     compute(b2); compute(b3).
//   Keeps 16-32 loads in flight nearly continuously per wave (vs one burst
//   then a full drain in R3-R7), raising aggregate outstanding bytes (Little's
//   law) without touching the verified MFMA fragment/D-layout core.

#define NTOT 6561
#define NL   81
#define CH   64
#define NSLOTS 451                       // sum over l of ceil((2l+1)/16)
#define WTB_BYTES (NL * CH * CH * 2)     // 663552

typedef __attribute__((ext_vector_type(8))) short bf16x8;
typedef __attribute__((ext_vector_type(4))) float f32x4;

// ---- Kernel A: bf16 interpolated weight table, wtb[l][o][i] (i contiguous) ----
__global__ __launch_bounds__(256) void interp_bf16(const float* __restrict__ w,
                                                   __hip_bfloat16* __restrict__ wtb) {
  int idx = blockIdx.x * 256 + threadIdx.x;   // 1296*256 = 331776 exact
  int l = idx >> 12;
  int o = (idx >> 6) & 63;
  int i = idx & 63;
  int cp; float f;
  if (l < 75) { cp = l / 5; f = (float)(l - cp * 5) * 0.2f; }
  else        { cp = 15;    f = (float)(l - 75) * 0.2f; }
  const float* wp = w + (size_t)(i * 64 + o) * 17 + cp;   // weight[i][o][cp]
  float v = (1.0f - f) * wp[0] + f * wp[1];
  wtb[(size_t)l * 4096 + o * 64 + i] = __float2bfloat16(v);
}

__device__ __forceinline__ void load_item(const float* __restrict__ xb,
                                          float (&xr)[16], int kg) {
#pragma unroll
  for (int ks = 0; ks < 2; ++ks)
#pragma unroll
    for (int j = 0; j < 8; ++j)
      xr[ks * 8 + j] = xb[(size_t)(ks * 32 + kg * 8 + j) * NTOT];
}

__device__ __forceinline__ void compute_store(const float (&xr)[16],
                                              const bf16x8 (&afrag)[2][4],
                                              float* __restrict__ ob,
                                              bool act, int kg) {
  bf16x8 bf[2];
#pragma unroll
  for (int ks = 0; ks < 2; ++ks)
#pragma unroll
    for (int j = 0; j < 8; ++j) {
      __hip_bfloat16 h = __float2bfloat16(xr[ks * 8 + j]);
      bf[ks][j] = *reinterpret_cast<short*>(&h);
    }
  f32x4 acc[4];
#pragma unroll
  for (int t = 0; t < 4; ++t) acc[t] = (f32x4)(0.0f);
#pragma unroll
  for (int ks = 0; ks < 2; ++ks)
#pragma unroll
    for (int t = 0; t < 4; ++t)
      acc[t] = __builtin_amdgcn_mfma_f32_16x16x32_bf16(afrag[ks][t], bf[ks], acc[t], 0, 0, 0);
  if (act) {
    // D layout (verified m89): col = lane&15, row = kg*4 + rg per 16-row tile
#pragma unroll
    for (int t = 0; t < 4; ++t)
#pragma unroll
      for (int rg = 0; rg < 4; ++rg)
        ob[(size_t)(t * 16 + kg * 4 + rg) * NTOT] = acc[t][rg];
  }
}

// ---- Kernel B: grid (902), block 256 = 4 waves; wave = (slot, 4 batches) ----
__global__ __launch_bounds__(256) void shconv_pipe(const float* __restrict__ x,
                                                   const __hip_bfloat16* __restrict__ wtb,
                                                   float* __restrict__ out) {
  const int wv   = threadIdx.x >> 6;
  const int lane = threadIdx.x & 63;
  const int m    = lane & 15;
  const int kg   = lane >> 4;
  const int wg   = (int)blockIdx.x * 4 + wv;   // 0..3607 = 451 slots * 8 batch-quads
  const int s    = wg >> 3;
  const int bq   = wg & 7;

  // slot -> (l, chunk): group g = l/8 has g+1 chunks per l; 4g(g+1) chunks before it
  int g = 0;
  while (g < 10 && 4 * (g + 1) * (g + 2) <= s) ++g;
  const int r = s - 4 * g * (g + 1);
  const int l = 8 * g + r / (g + 1);
  const int c = r - (l - 8 * g) * (g + 1);
  const int P = 2 * l + 1;

  const int p  = c * 16 + m;
  const int pl = (p < P) ? p : (P - 1);        // clamp tail loads in-bounds
  const bool act = (p < P);
  const size_t nbase = (size_t)l * l;

  // A-fragments: loaded once, reused across 4 batches
  const __hip_bfloat16* wl = wtb + (size_t)l * 4096;
  bf16x8 afrag[2][4];
#pragma unroll
  for (int ks = 0; ks < 2; ++ks)
#pragma unroll
    for (int t = 0; t < 4; ++t)
      afrag[ks][t] = *reinterpret_cast<const bf16x8*>(
          wl + (size_t)(t * 16 + m) * 64 + ks * 32 + kg * 8);

  const int b0 = bq * 4;
  const float* xp0 = x + (size_t)(b0 + 0) * CH * NTOT + nbase + pl;
  const float* xp1 = x + (size_t)(b0 + 1) * CH * NTOT + nbase + pl;
  const float* xp2 = x + (size_t)(b0 + 2) * CH * NTOT + nbase + pl;
  const float* xp3 = x + (size_t)(b0 + 3) * CH * NTOT + nbase + pl;
  float* op0 = out + (size_t)(b0 + 0) * CH * NTOT + nbase + p;
  float* op1 = out + (size_t)(b0 + 1) * CH * NTOT + nbase + p;
  float* op2 = out + (size_t)(b0 + 2) * CH * NTOT + nbase + p;
  float* op3 = out + (size_t)(b0 + 3) * CH * NTOT + nbase + p;

  // depth-2 software pipeline through two named buffers (rule #20 safe)
  float xrA[16], xrB[16];
  load_item(xp0, xrA, kg);
  load_item(xp1, xrB, kg);
  compute_store(xrA, afrag, op0, act, kg);
  load_item(xp2, xrA, kg);
  compute_store(xrB, afrag, op1, act, kg);
  load_item(xp3, xrB, kg);
  compute_store(xrA, afrag, op2, act, kg);
  compute_store(xrB, afrag, op3, act, kg);
}

// ---- Fallback (no workspace): R2's passing fp32 LDS kernel ----
__global__ __launch_bounds__(192) void shconv_fallback(const float* __restrict__ x,
                                                       const float* __restrict__ w,
                                                       float* __restrict__ out) {
  __shared__ float wl[2][64][64];
  const int l1 = blockIdx.x;
  const int l2 = 80 - l1;
  const int P1 = 2 * l1 + 1;
  const int P2 = (l1 == 40) ? 0 : 2 * l2 + 1;
  int cp1, cp2; float f1, f2;
  if (l1 < 75) { cp1 = l1 / 5; f1 = (float)(l1 - cp1 * 5) * 0.2f; }
  else         { cp1 = 15;     f1 = (float)(l1 - 75) * 0.2f; }
  if (l2 < 75) { cp2 = l2 / 5; f2 = (float)(l2 - cp2 * 5) * 0.2f; }
  else         { cp2 = 15;     f2 = (float)(l2 - 75) * 0.2f; }
  const int tid = threadIdx.x;
  for (int e = tid; e < 8192; e += 192) {
    int sel = e >> 12, rr = e & 4095, i = rr >> 6, o = rr & 63;
    int cp = sel ? cp2 : cp1;
    float f = sel ? f2 : f1;
    const float* wp = w + (size_t)(i * 64 + o) * 17 + cp;
    wl[sel][i][o] = (1.0f - f) * wp[0] + f * wp[1];
  }
  __syncthreads();
  const int Ptot = P1 + P2;
  if (tid >= Ptot) return;
  int sel, l, p;
  if (tid < P1) { sel = 0; l = l1; p = tid; }
  else          { sel = 1; l = l2; p = tid - P1; }
  const size_t nidx = (size_t)(l * l) + p;
  const int b0 = blockIdx.y, b1 = b0 + 16;
  const float* x0 = x + (size_t)b0 * CH * NTOT + nidx;
  const float* x1 = x + (size_t)b1 * CH * NTOT + nidx;
  float acc0[64], acc1[64];
#pragma unroll
  for (int o = 0; o < 64; ++o) { acc0[o] = 0.f; acc1[o] = 0.f; }
  const float* wbase = &wl[sel][0][0];
#pragma unroll 4
  for (int i = 0; i < 64; ++i) {
    float xv0 = x0[(size_t)i * NTOT];
    float xv1 = x1[(size_t)i * NTOT];
    const float* wr = wbase + i * 64;
#pragma unroll
    for (int o = 0; o < 64; o += 4) {
      float4 wv = *(const float4*)(wr + o);
      acc0[o]     = fmaf(xv0, wv.x, acc0[o]);
      acc0[o + 1] = fmaf(xv0, wv.y, acc0[o + 1]);
      acc0[o + 2] = fmaf(xv0, wv.z, acc0[o + 2]);
      acc0[o + 3] = fmaf(xv0, wv.w, acc0[o + 3]);
      acc1[o]     = fmaf(xv1, wv.x, acc1[o]);
      acc1[o + 1] = fmaf(xv1, wv.y, acc1[o + 1]);
      acc1[o + 2] = fmaf(xv1, wv.z, acc1[o + 2]);
      acc1[o + 3] = fmaf(xv1, wv.w, acc1[o + 3]);
    }
  }
  float* o0 = out + (size_t)b0 * CH * NTOT + nidx;
  float* o1 = out + (size_t)b1 * CH * NTOT + nidx;
#pragma unroll
  for (int o = 0; o < 64; ++o) {
    o0[(size_t)o * NTOT] = acc0[o];
    o1[(size_t)o * NTOT] = acc1[o];
  }
}

extern "C" void kernel_launch(void* const* d_in, const int* in_sizes, int n_in,
                              void* d_out, int out_size, void* d_ws, size_t ws_size,
                              hipStream_t stream) {
  const float* x = (const float*)d_in[0];
  const float* w = (const float*)d_in[1];
  float* out = (float*)d_out;

  if (ws_size >= (size_t)WTB_BYTES && d_ws != nullptr) {
    __hip_bfloat16* wtb = (__hip_bfloat16*)d_ws;
    hipLaunchKernelGGL(interp_bf16, dim3(1296), dim3(256), 0, stream, w, wtb);
    hipLaunchKernelGGL(shconv_pipe, dim3(902), dim3(256), 0, stream, x, wtb, out);
  } else {
    hipLaunchKernelGGL(shconv_fallback, dim3(41, 16), dim3(192), 0, stream, x, w, out);
  }
}

// Round 10
// 36.163 us; speedup vs baseline: 1.5150x; 1.5150x over previous
//
#include <hip/hip_runtime.h>
#include <hip/hip_bf16.h>

// SHConv via bf16 MFMA: out[b,o,n] = sum_i x[b,i,n] * W_{l(n)}[i,o], l(n)=floor(sqrt(n))
// x: (32,64,6561) f32, weight: (64,64,17,1) f32, out: (32,64,6561) f32
//
// R9 = R8's depth-2 pipelined wave (4 batches, A-fragments loaded once) with
// R4's slot-major block mapping restored: block = 4 CONSECUTIVE slots (adjacent
// 16-pos chunks of one degree) x one batch-quad. Adjacent chunks co-resident
// -> L2 merges the 64B half-lines on both loads and stores (R8 split them
// across blocks -> ~2x line amplification, FETCH 84.7MB / WRITE 77.8MB).

#define NTOT 6561
#define NL   81
#define CH   64
#define NSLOTS 451                       // sum over l of ceil((2l+1)/16)
#define WTB_BYTES (NL * CH * CH * 2)     // 663552

typedef __attribute__((ext_vector_type(8))) short bf16x8;
typedef __attribute__((ext_vector_type(4))) float f32x4;

// ---- Kernel A: bf16 interpolated weight table, wtb[l][o][i] (i contiguous) ----
__global__ __launch_bounds__(256) void interp_bf16(const float* __restrict__ w,
                                                   __hip_bfloat16* __restrict__ wtb) {
  int idx = blockIdx.x * 256 + threadIdx.x;   // 1296*256 = 331776 exact
  int l = idx >> 12;
  int o = (idx >> 6) & 63;
  int i = idx & 63;
  int cp; float f;
  if (l < 75) { cp = l / 5; f = (float)(l - cp * 5) * 0.2f; }
  else        { cp = 15;    f = (float)(l - 75) * 0.2f; }
  const float* wp = w + (size_t)(i * 64 + o) * 17 + cp;   // weight[i][o][cp]
  float v = (1.0f - f) * wp[0] + f * wp[1];
  wtb[(size_t)l * 4096 + o * 64 + i] = __float2bfloat16(v);
}

__device__ __forceinline__ void load_item(const float* __restrict__ xb,
                                          float (&xr)[16], int kg) {
#pragma unroll
  for (int ks = 0; ks < 2; ++ks)
#pragma unroll
    for (int j = 0; j < 8; ++j)
      xr[ks * 8 + j] = xb[(size_t)(ks * 32 + kg * 8 + j) * NTOT];
}

__device__ __forceinline__ void compute_store(const float (&xr)[16],
                                              const bf16x8 (&afrag)[2][4],
                                              float* __restrict__ ob,
                                              bool act, int kg) {
  bf16x8 bf[2];
#pragma unroll
  for (int ks = 0; ks < 2; ++ks)
#pragma unroll
    for (int j = 0; j < 8; ++j) {
      __hip_bfloat16 h = __float2bfloat16(xr[ks * 8 + j]);
      bf[ks][j] = *reinterpret_cast<short*>(&h);
    }
  f32x4 acc[4];
#pragma unroll
  for (int t = 0; t < 4; ++t) acc[t] = (f32x4)(0.0f);
#pragma unroll
  for (int ks = 0; ks < 2; ++ks)
#pragma unroll
    for (int t = 0; t < 4; ++t)
      acc[t] = __builtin_amdgcn_mfma_f32_16x16x32_bf16(afrag[ks][t], bf[ks], acc[t], 0, 0, 0);
  if (act) {
    // D layout (verified m89): col = lane&15, row = kg*4 + rg per 16-row tile
#pragma unroll
    for (int t = 0; t < 4; ++t)
#pragma unroll
      for (int rg = 0; rg < 4; ++rg)
        ob[(size_t)(t * 16 + kg * 4 + rg) * NTOT] = acc[t][rg];
  }
}

// ---- Kernel B: grid (113, 8), block 256 = 4 waves = 4 CONSECUTIVE slots ----
__global__ __launch_bounds__(256) void shconv_pipe(const float* __restrict__ x,
                                                   const __hip_bfloat16* __restrict__ wtb,
                                                   float* __restrict__ out) {
  const int wv   = threadIdx.x >> 6;
  const int lane = threadIdx.x & 63;
  const int m    = lane & 15;
  const int kg   = lane >> 4;
  const int s    = (int)blockIdx.x * 4 + wv;   // consecutive slots within block
  if (s >= NSLOTS) return;
  const int bq   = blockIdx.y;                 // batch quad 0..7

  // slot -> (l, chunk): group g = l/8 has g+1 chunks per l; 4g(g+1) chunks before it
  int g = 0;
  while (g < 10 && 4 * (g + 1) * (g + 2) <= s) ++g;
  const int r = s - 4 * g * (g + 1);
  const int l = 8 * g + r / (g + 1);
  const int c = r - (l - 8 * g) * (g + 1);
  const int P = 2 * l + 1;

  const int p  = c * 16 + m;
  const int pl = (p < P) ? p : (P - 1);        // clamp tail loads in-bounds
  const bool act = (p < P);
  const size_t nbase = (size_t)l * l;

  // A-fragments: loaded once, reused across 4 batches
  const __hip_bfloat16* wl = wtb + (size_t)l * 4096;
  bf16x8 afrag[2][4];
#pragma unroll
  for (int ks = 0; ks < 2; ++ks)
#pragma unroll
    for (int t = 0; t < 4; ++t)
      afrag[ks][t] = *reinterpret_cast<const bf16x8*>(
          wl + (size_t)(t * 16 + m) * 64 + ks * 32 + kg * 8);

  const int b0 = bq * 4;
  const float* xp0 = x + (size_t)(b0 + 0) * CH * NTOT + nbase + pl;
  const float* xp1 = x + (size_t)(b0 + 1) * CH * NTOT + nbase + pl;
  const float* xp2 = x + (size_t)(b0 + 2) * CH * NTOT + nbase + pl;
  const float* xp3 = x + (size_t)(b0 + 3) * CH * NTOT + nbase + pl;
  float* op0 = out + (size_t)(b0 + 0) * CH * NTOT + nbase + p;
  float* op1 = out + (size_t)(b0 + 1) * CH * NTOT + nbase + p;
  float* op2 = out + (size_t)(b0 + 2) * CH * NTOT + nbase + p;
  float* op3 = out + (size_t)(b0 + 3) * CH * NTOT + nbase + p;

  // depth-2 software pipeline through two named buffers (rule #20 safe)
  float xrA[16], xrB[16];
  load_item(xp0, xrA, kg);
  load_item(xp1, xrB, kg);
  compute_store(xrA, afrag, op0, act, kg);
  load_item(xp2, xrA, kg);
  compute_store(xrB, afrag, op1, act, kg);
  load_item(xp3, xrB, kg);
  compute_store(xrA, afrag, op2, act, kg);
  compute_store(xrB, afrag, op3, act, kg);
}

// ---- Fallback (no workspace): R2's passing fp32 LDS kernel ----
__global__ __launch_bounds__(192) void shconv_fallback(const float* __restrict__ x,
                                                       const float* __restrict__ w,
                                                       float* __restrict__ out) {
  __shared__ float wl[2][64][64];
  const int l1 = blockIdx.x;
  const int l2 = 80 - l1;
  const int P1 = 2 * l1 + 1;
  const int P2 = (l1 == 40) ? 0 : 2 * l2 + 1;
  int cp1, cp2; float f1, f2;
  if (l1 < 75) { cp1 = l1 / 5; f1 = (float)(l1 - cp1 * 5) * 0.2f; }
  else         { cp1 = 15;     f1 = (float)(l1 - 75) * 0.2f; }
  if (l2 < 75) { cp2 = l2 / 5; f2 = (float)(l2 - cp2 * 5) * 0.2f; }
  else         { cp2 = 15;     f2 = (float)(l2 - 75) * 0.2f; }
  const int tid = threadIdx.x;
  for (int e = tid; e < 8192; e += 192) {
    int sel = e >> 12, rr = e & 4095, i = rr >> 6, o = rr & 63;
    int cp = sel ? cp2 : cp1;
    float f = sel ? f2 : f1;
    const float* wp = w + (size_t)(i * 64 + o) * 17 + cp;
    wl[sel][i][o] = (1.0f - f) * wp[0] + f * wp[1];
  }
  __syncthreads();
  const int Ptot = P1 + P2;
  if (tid >= Ptot) return;
  int sel, l, p;
  if (tid < P1) { sel = 0; l = l1; p = tid; }
  else          { sel = 1; l = l2; p = tid - P1; }
  const size_t nidx = (size_t)(l * l) + p;
  const int b0 = blockIdx.y, b1 = b0 + 16;
  const float* x0 = x + (size_t)b0 * CH * NTOT + nidx;
  const float* x1 = x + (size_t)b1 * CH * NTOT + nidx;
  float acc0[64], acc1[64];
#pragma unroll
  for (int o = 0; o < 64; ++o) { acc0[o] = 0.f; acc1[o] = 0.f; }
  const float* wbase = &wl[sel][0][0];
#pragma unroll 4
  for (int i = 0; i < 64; ++i) {
    float xv0 = x0[(size_t)i * NTOT];
    float xv1 = x1[(size_t)i * NTOT];
    const float* wr = wbase + i * 64;
#pragma unroll
    for (int o = 0; o < 64; o += 4) {
      float4 wv = *(const float4*)(wr + o);
      acc0[o]     = fmaf(xv0, wv.x, acc0[o]);
      acc0[o + 1] = fmaf(xv0, wv.y, acc0[o + 1]);
      acc0[o + 2] = fmaf(xv0, wv.z, acc0[o + 2]);
      acc0[o + 3] = fmaf(xv0, wv.w, acc0[o + 3]);
      acc1[o]     = fmaf(xv1, wv.x, acc1[o]);
      acc1[o + 1] = fmaf(xv1, wv.y, acc1[o + 1]);
      acc1[o + 2] = fmaf(xv1, wv.z, acc1[o + 2]);
      acc1[o + 3] = fmaf(xv1, wv.w, acc1[o + 3]);
    }
  }
  float* o0 = out + (size_t)b0 * CH * NTOT + nidx;
  float* o1 = out + (size_t)b1 * CH * NTOT + nidx;
#pragma unroll
  for (int o = 0; o < 64; ++o) {
    o0[(size_t)o * NTOT] = acc0[o];
    o1[(size_t)o * NTOT] = acc1[o];
  }
}

extern "C" void kernel_launch(void* const* d_in, const int* in_sizes, int n_in,
                              void* d_out, int out_size, void* d_ws, size_t ws_size,
                              hipStream_t stream) {
  const float* x = (const float*)d_in[0];
  const float* w = (const float*)d_in[1];
  float* out = (float*)d_out;

  if (ws_size >= (size_t)WTB_BYTES && d_ws != nullptr) {
    __hip_bfloat16* wtb = (__hip_bfloat16*)d_ws;
    hipLaunchKernelGGL(interp_bf16, dim3(1296), dim3(256), 0, stream, w, wtb);
    hipLaunchKernelGGL(shconv_pipe, dim3(113, 8), dim3(256), 0, stream, x, wtb, out);
  } else {
    hipLaunchKernelGGL(shconv_fallback, dim3(41, 16), dim3(192), 0, stream, x, w, out);
  }
}

// Round 12
// 35.715 us; speedup vs baseline: 1.5340x; 1.0126x over previous
//
#include <hip/hip_runtime.h>
#include <hip/hip_bf16.h>

// SHConv via bf16 MFMA: out[b,o,n] = sum_i x[b,i,n] * W_{l(n)}[i,o], l(n)=floor(sqrt(n))
// x: (32,64,6561) f32, weight: (64,64,17,1) f32, out: (32,64,6561) f32
//
// R11 = R10 (full-line float2 requests via column-permutation, no shuffles)
// with two window-math fixes:
//  (a) windows tile each degree on the GLOBAL EVEN grid: base = l*l & ~1,
//      window c covers [base+32c, base+32c+32). Disjoint, complete coverage
//      of [l*l, l*l+P) under masks; slot count per degree unchanged.
//  (b) array-tail clamp: lane with gp == NTOT-1 loads shifted pair (n2=NTOT-2),
//      so position gp's value lands in .y -> its result is in accB; store accB
//      to op[0] under the `sh` flag (exec-masked, free in non-tail waves).
// Keeps R9/R10: 4 batches/wave (A-frags once), depth-2 pipeline, named buffers,
// slot-major block mapping, verified MFMA fragment/D-layout core.

#define NTOT 6561
#define NL   81
#define CH   64
#define NSLOT32 246                      // sum over l of ceil((2l+1)/32)
#define WTB_BYTES (NL * CH * CH * 2)     // 663552

typedef __attribute__((ext_vector_type(8))) short bf16x8;
typedef __attribute__((ext_vector_type(4))) float f32x4;

// ---- Kernel A: bf16 interpolated weight table, wtb[l][o][i] (i contiguous) ----
__global__ __launch_bounds__(256) void interp_bf16(const float* __restrict__ w,
                                                   __hip_bfloat16* __restrict__ wtb) {
  int idx = blockIdx.x * 256 + threadIdx.x;   // 1296*256 = 331776 exact
  int l = idx >> 12;
  int o = (idx >> 6) & 63;
  int i = idx & 63;
  int cp; float f;
  if (l < 75) { cp = l / 5; f = (float)(l - cp * 5) * 0.2f; }
  else        { cp = 15;    f = (float)(l - 75) * 0.2f; }
  const float* wp = w + (size_t)(i * 64 + o) * 17 + cp;   // weight[i][o][cp]
  float v = (1.0f - f) * wp[0] + f * wp[1];
  wtb[(size_t)l * 4096 + o * 64 + i] = __float2bfloat16(v);
}

__device__ __forceinline__ void load_item2(const float* __restrict__ xb,
                                           float2 (&xr)[16], int kg) {
#pragma unroll
  for (int ks = 0; ks < 2; ++ks)
#pragma unroll
    for (int j = 0; j < 8; ++j)
      __builtin_memcpy(&xr[ks * 8 + j],
                       xb + (size_t)(ks * 32 + kg * 8 + j) * NTOT, 8);
}

__device__ __forceinline__ void compute_store2(const float2 (&xr)[16],
                                               const bf16x8 (&afrag)[2][4],
                                               float* __restrict__ ob,  // out + gp
                                               bool v0, bool v1, bool sh, int kg) {
  bf16x8 bfA[2], bfB[2];
#pragma unroll
  for (int ks = 0; ks < 2; ++ks)
#pragma unroll
    for (int j = 0; j < 8; ++j) {
      __hip_bfloat16 hA = __float2bfloat16(xr[ks * 8 + j].x);
      __hip_bfloat16 hB = __float2bfloat16(xr[ks * 8 + j].y);
      bfA[ks][j] = *reinterpret_cast<short*>(&hA);
      bfB[ks][j] = *reinterpret_cast<short*>(&hB);
    }
  f32x4 accA[4], accB[4];
#pragma unroll
  for (int t = 0; t < 4; ++t) { accA[t] = (f32x4)(0.0f); accB[t] = (f32x4)(0.0f); }
#pragma unroll
  for (int ks = 0; ks < 2; ++ks)
#pragma unroll
    for (int t = 0; t < 4; ++t) {
      accA[t] = __builtin_amdgcn_mfma_f32_16x16x32_bf16(afrag[ks][t], bfA[ks], accA[t], 0, 0, 0);
      accB[t] = __builtin_amdgcn_mfma_f32_16x16x32_bf16(afrag[ks][t], bfB[ks], accB[t], 0, 0, 0);
    }
  // D layout (verified m89): col = lane&15, row = kg*4 + rg per 16-row tile.
  // Col m of A = pos gp, col m of B = pos gp+1 -> lane-local float2 store.
#pragma unroll
  for (int t = 0; t < 4; ++t)
#pragma unroll
    for (int rg = 0; rg < 4; ++rg) {
      float* op = ob + (size_t)(t * 16 + kg * 4 + rg) * NTOT;
      if (v0 && v1) {
        float2 sv; sv.x = accA[t][rg]; sv.y = accB[t][rg];
        __builtin_memcpy(op, &sv, 8);               // full-line run
      } else if (v1) {
        op[1] = accB[t][rg];                        // odd-l window head
      } else if (v0) {
        op[0] = sh ? accB[t][rg] : accA[t][rg];     // tail; sh = shifted load pair
      }
    }
}

// ---- Kernel B: grid (62, 8), block 256 = 4 waves = 4 CONSECUTIVE slot32s ----
__global__ __launch_bounds__(256) void shconv_pipe2(const float* __restrict__ x,
                                                    const __hip_bfloat16* __restrict__ wtb,
                                                    float* __restrict__ out) {
  const int wv   = threadIdx.x >> 6;
  const int lane = threadIdx.x & 63;
  const int m    = lane & 15;
  const int kg   = lane >> 4;
  const int s    = (int)blockIdx.x * 4 + wv;   // consecutive slot32s in block
  if (s >= NSLOT32) return;
  const int bq   = blockIdx.y;                 // batch quad 0..7

  // slot32 -> (l, c): degree-group g = l/16 has g+1 chunks; 8g(g+1) slots before it
  int l, c;
  if (s >= 240) { l = 80; c = s - 240; }
  else {
    int g = 0;
    while (g < 4 && 8 * (g + 1) * (g + 2) <= s) ++g;
    const int r = s - 8 * g * (g + 1);
    const int q = r / (g + 1);
    l = 16 * g + q;
    c = r - q * (g + 1);
  }
  const int P    = 2 * l + 1;
  const int lo   = l * l;                      // first valid position of degree
  const int end  = lo + P;                     // one past last valid
  const int base = lo & ~1;                    // even grid origin for this degree
  const int w0   = base + c * 32;              // this window's even-aligned start

  const int gp  = w0 + 2 * m;                  // lane's position pair (gp, gp+1)
  const bool v0 = (gp     >= lo) && (gp     < end);
  const bool v1 = (gp + 1 >= lo) && (gp + 1 < end);
  int n2 = gp; bool sh = false;
  if (n2 > NTOT - 2) {                         // clamp loads in-array
    sh = (gp == NTOT - 1) && v0;               // shifted pair: gp's value in .y
    n2 = NTOT - 2;
  }

  // A-fragments: loaded once, reused across 4 batches x 2 chunks
  const __hip_bfloat16* wl = wtb + (size_t)l * 4096;
  bf16x8 afrag[2][4];
#pragma unroll
  for (int ks = 0; ks < 2; ++ks)
#pragma unroll
    for (int t = 0; t < 4; ++t)
      afrag[ks][t] = *reinterpret_cast<const bf16x8*>(
          wl + (size_t)(t * 16 + m) * 64 + ks * 32 + kg * 8);

  const int b0 = bq * 4;
  const float* xp0 = x + (size_t)(b0 + 0) * CH * NTOT + n2;
  const float* xp1 = x + (size_t)(b0 + 1) * CH * NTOT + n2;
  const float* xp2 = x + (size_t)(b0 + 2) * CH * NTOT + n2;
  const float* xp3 = x + (size_t)(b0 + 3) * CH * NTOT + n2;
  float* op0 = out + (size_t)(b0 + 0) * CH * NTOT + gp;
  float* op1 = out + (size_t)(b0 + 1) * CH * NTOT + gp;
  float* op2 = out + (size_t)(b0 + 2) * CH * NTOT + gp;
  float* op3 = out + (size_t)(b0 + 3) * CH * NTOT + gp;

  // depth-2 software pipeline through two named buffers (rule #20 safe)
  float2 xrA[16], xrB[16];
  load_item2(xp0, xrA, kg);
  load_item2(xp1, xrB, kg);
  compute_store2(xrA, afrag, op0, v0, v1, sh, kg);
  load_item2(xp2, xrA, kg);
  compute_store2(xrB, afrag, op1, v0, v1, sh, kg);
  load_item2(xp3, xrB, kg);
  compute_store2(xrA, afrag, op2, v0, v1, sh, kg);
  compute_store2(xrB, afrag, op3, v0, v1, sh, kg);
}

// ---- Fallback (no workspace): R2's passing fp32 LDS kernel ----
__global__ __launch_bounds__(192) void shconv_fallback(const float* __restrict__ x,
                                                       const float* __restrict__ w,
                                                       float* __restrict__ out) {
  __shared__ float wl[2][64][64];
  const int l1 = blockIdx.x;
  const int l2 = 80 - l1;
  const int P1 = 2 * l1 + 1;
  const int P2 = (l1 == 40) ? 0 : 2 * l2 + 1;
  int cp1, cp2; float f1, f2;
  if (l1 < 75) { cp1 = l1 / 5; f1 = (float)(l1 - cp1 * 5) * 0.2f; }
  else         { cp1 = 15;     f1 = (float)(l1 - 75) * 0.2f; }
  if (l2 < 75) { cp2 = l2 / 5; f2 = (float)(l2 - cp2 * 5) * 0.2f; }
  else         { cp2 = 15;     f2 = (float)(l2 - 75) * 0.2f; }
  const int tid = threadIdx.x;
  for (int e = tid; e < 8192; e += 192) {
    int sel = e >> 12, rr = e & 4095, i = rr >> 6, o = rr & 63;
    int cp = sel ? cp2 : cp1;
    float f = sel ? f2 : f1;
    const float* wp = w + (size_t)(i * 64 + o) * 17 + cp;
    wl[sel][i][o] = (1.0f - f) * wp[0] + f * wp[1];
  }
  __syncthreads();
  const int Ptot = P1 + P2;
  if (tid >= Ptot) return;
  int sel, l, p;
  if (tid < P1) { sel = 0; l = l1; p = tid; }
  else          { sel = 1; l = l2; p = tid - P1; }
  const size_t nidx = (size_t)(l * l) + p;
  const int b0 = blockIdx.y, b1 = b0 + 16;
  const float* x0 = x + (size_t)b0 * CH * NTOT + nidx;
  const float* x1 = x + (size_t)b1 * CH * NTOT + nidx;
  float acc0[64], acc1[64];
#pragma unroll
  for (int o = 0; o < 64; ++o) { acc0[o] = 0.f; acc1[o] = 0.f; }
  const float* wbase = &wl[sel][0][0];
#pragma unroll 4
  for (int i = 0; i < 64; ++i) {
    float xv0 = x0[(size_t)i * NTOT];
    float xv1 = x1[(size_t)i * NTOT];
    const float* wr = wbase + i * 64;
#pragma unroll
    for (int o = 0; o < 64; o += 4) {
      float4 wv = *(const float4*)(wr + o);
      acc0[o]     = fmaf(xv0, wv.x, acc0[o]);
      acc0[o + 1] = fmaf(xv0, wv.y, acc0[o + 1]);
      acc0[o + 2] = fmaf(xv0, wv.z, acc0[o + 2]);
      acc0[o + 3] = fmaf(xv0, wv.w, acc0[o + 3]);
      acc1[o]     = fmaf(xv1, wv.x, acc1[o]);
      acc1[o + 1] = fmaf(xv1, wv.y, acc1[o + 1]);
      acc1[o + 2] = fmaf(xv1, wv.z, acc1[o + 2]);
      acc1[o + 3] = fmaf(xv1, wv.w, acc1[o + 3]);
    }
  }
  float* o0 = out + (size_t)b0 * CH * NTOT + nidx;
  float* o1 = out + (size_t)b1 * CH * NTOT + nidx;
#pragma unroll
  for (int o = 0; o < 64; ++o) {
    o0[(size_t)o * NTOT] = acc0[o];
    o1[(size_t)o * NTOT] = acc1[o];
  }
}

extern "C" void kernel_launch(void* const* d_in, const int* in_sizes, int n_in,
                              void* d_out, int out_size, void* d_ws, size_t ws_size,
                              hipStream_t stream) {
  const float* x = (const float*)d_in[0];
  const float* w = (const float*)d_in[1];
  float* out = (float*)d_out;

  if (ws_size >= (size_t)WTB_BYTES && d_ws != nullptr) {
    __hip_bfloat16* wtb = (__hip_bfloat16*)d_ws;
    hipLaunchKernelGGL(interp_bf16, dim3(1296), dim3(256), 0, stream, w, wtb);
    hipLaunchKernelGGL(shconv_pipe2, dim3(62, 8), dim3(256), 0, stream, x, wtb, out);
  } else {
    hipLaunchKernelGGL(shconv_fallback, dim3(41, 16), dim3(192), 0, stream, x, w, out);
  }
}